// Round 3
// baseline (8211.050 us; speedup 1.0000x reference)
//
#include <hip/hip_runtime.h>

// ============================================================================
// RSSM (DynamicsModel) on MI355X — round 3.
//   * prior branch (ha GEMM, prior GEMM, prior rsample) moved OFF the serial
//     scan: batched over all B*T rows after the scan (gru logs h into Hall)
//   * posterior rsample fused into post-GEMM epilogue via column-interleaved
//     W_post (qm_j / qlv_j 16 cols apart -> same lane, adjacent ni frags)
//   * per-step launches: sa, gi/gh, gru, ho(split-K4), reduce, post+sample
// ============================================================================

typedef __attribute__((ext_vector_type(8))) short bf16x8;
typedef __attribute__((ext_vector_type(4))) float f32x4;
typedef __attribute__((ext_vector_type(4))) short s16x4;

#define DEVI static __device__ __forceinline__

DEVI float bf2f(short s) { union { float f; unsigned u; } v; v.u = ((unsigned)(unsigned short)s) << 16; return v.f; }
DEVI short f2bf(float f) {
  union { float f; unsigned u; } v; v.f = f;
  unsigned r = v.u + 0x7FFFu + ((v.u >> 16) & 1u);   // RNE
  return (short)(r >> 16);
}

#define Bsz 256
#define Tsz 64
#define Hsz 2048
#define Ssz 512
#define Asz 64
#define Esz 2048
#define TM1 63

#define PSH (256 * 2048)

#define OUT_PS  33554432L
#define OUT_QS  41943040L
#define OUT_PM  50331648L
#define OUT_PLV 58589184L
#define OUT_QM  66846720L
#define OUT_QLV 75104256L

struct GArg {
  const short* A; const short* Bt; const float* bias; const short* Ci;
  float* oF; short* oB;
  int lda, ldb, ldoF, ldoB; long ldci, pstride;
};

// ---------------------------------------------------------------------------
// generic bf16 GEMM (128x128 tile, BK=64, dbuf, swizzled LDS, counted vmcnt)
// blockIdx.z: gemm = glog ? z&1 : 0 ; kc = z >> glog (split-K chunk)
// ---------------------------------------------------------------------------
template<int HASBIAS, int HASCI, int RELU, int OUTF, int OUTB>
__global__ __launch_bounds__(256) void gemm_bt(GArg g0, GArg g1, int glog, int kcK) {
  const int z = blockIdx.z;
  const int gemm = glog ? (z & 1) : 0;
  const int kc = z >> glog;
  const GArg g = gemm ? g1 : g0;
  const short* __restrict__ Ag = g.A + (long)kc * kcK;
  const short* __restrict__ Bg = g.Bt + (long)kc * kcK;
  __shared__ __align__(16) short As[2][128 * 64];
  __shared__ __align__(16) short Bs[2][128 * 64];
  const int tid = threadIdx.x;
  const int w = tid >> 6, l = tid & 63;
  const int bm0 = blockIdx.y << 7, bn0 = blockIdx.x << 7;
  const int fc = l & 15, fh = l >> 4;
  const int wr = (w >> 1) << 6, wc = (w & 1) << 6;
  const int rx = fc & 7;

  const int srccol = ((l & 7) ^ ((l >> 3) & 7)) << 3;
  long aoff[4], boff[4];
#pragma unroll
  for (int i = 0; i < 4; ++i) {
    const int row = (((i << 2) + w) << 3) + (l >> 3);
    aoff[i] = (long)(bm0 + row) * g.lda + srccol;
    boff[i] = (long)(bn0 + row) * g.ldb + srccol;
  }

  f32x4 acc[4][4];
#pragma unroll
  for (int i = 0; i < 4; ++i)
#pragma unroll
    for (int j = 0; j < 4; ++j) acc[i][j] = f32x4{0.f, 0.f, 0.f, 0.f};

  auto STAGE = [&](int kt, int buf) {
#pragma unroll
    for (int i = 0; i < 4; ++i) {
      const int ib = ((i << 2) + w) << 10;
      __builtin_amdgcn_global_load_lds(
          (const __attribute__((address_space(1))) void*)(Ag + aoff[i] + (kt << 6)),
          (__attribute__((address_space(3))) void*)((char*)&As[buf][0] + ib), 16, 0, 0);
      __builtin_amdgcn_global_load_lds(
          (const __attribute__((address_space(1))) void*)(Bg + boff[i] + (kt << 6)),
          (__attribute__((address_space(3))) void*)((char*)&Bs[buf][0] + ib), 16, 0, 0);
    }
  };
  auto COMPUTE = [&](int buf) {
#pragma unroll
    for (int kk = 0; kk < 2; ++kk) {
      bf16x8 af[4], bb[4];
#pragma unroll
      for (int mi = 0; mi < 4; ++mi)
        af[mi] = *(const bf16x8*)&As[buf][(wr + (mi << 4) + fc) * 64 + ((((kk << 2) + fh) ^ rx) << 3)];
#pragma unroll
      for (int ni = 0; ni < 4; ++ni)
        bb[ni] = *(const bf16x8*)&Bs[buf][(wc + (ni << 4) + fc) * 64 + ((((kk << 2) + fh) ^ rx) << 3)];
#pragma unroll
      for (int mi = 0; mi < 4; ++mi)
#pragma unroll
        for (int ni = 0; ni < 4; ++ni)
          acc[mi][ni] = __builtin_amdgcn_mfma_f32_16x16x32_bf16(af[mi], bb[ni], acc[mi][ni], 0, 0, 0);
    }
  };

  const int nk = kcK >> 6;
  STAGE(0, 0);
  for (int kt = 0; kt < nk - 1; ++kt) {
    STAGE(kt + 1, (kt + 1) & 1);
    asm volatile("s_waitcnt vmcnt(8)" ::: "memory");
    __builtin_amdgcn_s_barrier();
    __builtin_amdgcn_sched_barrier(0);
    COMPUTE(kt & 1);
    asm volatile("s_waitcnt lgkmcnt(0)" ::: "memory");
    __builtin_amdgcn_s_barrier();
  }
  asm volatile("s_waitcnt vmcnt(0)" ::: "memory");
  __builtin_amdgcn_s_barrier();
  __builtin_amdgcn_sched_barrier(0);
  COMPUTE((nk - 1) & 1);

  float* oF = OUTF ? (g.oF + (long)kc * g.pstride) : (float*)nullptr;
#pragma unroll
  for (int mi = 0; mi < 4; ++mi) {
#pragma unroll
    for (int ni = 0; ni < 4; ++ni) {
      const int n = bn0 + wc + (ni << 4) + fc;
      float bv = 0.f;
      if (HASBIAS) bv = g.bias[n];
#pragma unroll
      for (int r = 0; r < 4; ++r) {
        const int m = bm0 + wr + (mi << 4) + (fh << 2) + r;
        float v = acc[mi][ni][r] + bv;
        if (HASCI) v += bf2f(g.Ci[(long)m * g.ldci + n]);
        if (RELU) v = fmaxf(v, 0.f);
        if (OUTF) oF[(long)m * g.ldoF + n] = v;
        if (OUTB) g.oB[(long)m * g.ldoB + n] = f2bf(v);
      }
    }
  }
}

// ---------------------------------------------------------------------------
// GEMM + fused rsample epilogue. B-operand is the column-PERMUTED [1024,2048]
// weight: output col n' = (j>>4)*32 + is_lv*16 + (j&15)  (j = state index).
// Lane pairing: ni even -> mean, ni+1 -> logvar, same j.
// PERSTEP=1: rows are batch (M=256), t = t_arg, also writes s_b.
// PERSTEP=0: rows m = b*64+t (M=16384), t==63 rows skipped.
// lda = ldb = 2048, K = 2048 fixed.
// ---------------------------------------------------------------------------
template<int PERSTEP>
__global__ __launch_bounds__(256) void gemm_sample(
    const short* __restrict__ A, const short* __restrict__ Bt,
    const float* __restrict__ bias, const float* __restrict__ noise,
    float* __restrict__ out, short* __restrict__ sbOut,
    long outS, long outM, long outLV, int t_arg) {
  __shared__ __align__(16) short As[2][128 * 64];
  __shared__ __align__(16) short Bs[2][128 * 64];
  const int tid = threadIdx.x;
  const int w = tid >> 6, l = tid & 63;
  const int bm0 = blockIdx.y << 7, bn0 = blockIdx.x << 7;
  const int fc = l & 15, fh = l >> 4;
  const int wr = (w >> 1) << 6, wc = (w & 1) << 6;
  const int rx = fc & 7;

  const int srccol = ((l & 7) ^ ((l >> 3) & 7)) << 3;
  long aoff[4], boff[4];
#pragma unroll
  for (int i = 0; i < 4; ++i) {
    const int row = (((i << 2) + w) << 3) + (l >> 3);
    aoff[i] = (long)(bm0 + row) * Hsz + srccol;
    boff[i] = (long)(bn0 + row) * Hsz + srccol;
  }

  f32x4 acc[4][4];
#pragma unroll
  for (int i = 0; i < 4; ++i)
#pragma unroll
    for (int j = 0; j < 4; ++j) acc[i][j] = f32x4{0.f, 0.f, 0.f, 0.f};

  auto STAGE = [&](int kt, int buf) {
#pragma unroll
    for (int i = 0; i < 4; ++i) {
      const int ib = ((i << 2) + w) << 10;
      __builtin_amdgcn_global_load_lds(
          (const __attribute__((address_space(1))) void*)(A + aoff[i] + (kt << 6)),
          (__attribute__((address_space(3))) void*)((char*)&As[buf][0] + ib), 16, 0, 0);
      __builtin_amdgcn_global_load_lds(
          (const __attribute__((address_space(1))) void*)(Bt + boff[i] + (kt << 6)),
          (__attribute__((address_space(3))) void*)((char*)&Bs[buf][0] + ib), 16, 0, 0);
    }
  };
  auto COMPUTE = [&](int buf) {
#pragma unroll
    for (int kk = 0; kk < 2; ++kk) {
      bf16x8 af[4], bb[4];
#pragma unroll
      for (int mi = 0; mi < 4; ++mi)
        af[mi] = *(const bf16x8*)&As[buf][(wr + (mi << 4) + fc) * 64 + ((((kk << 2) + fh) ^ rx) << 3)];
#pragma unroll
      for (int ni = 0; ni < 4; ++ni)
        bb[ni] = *(const bf16x8*)&Bs[buf][(wc + (ni << 4) + fc) * 64 + ((((kk << 2) + fh) ^ rx) << 3)];
#pragma unroll
      for (int mi = 0; mi < 4; ++mi)
#pragma unroll
        for (int ni = 0; ni < 4; ++ni)
          acc[mi][ni] = __builtin_amdgcn_mfma_f32_16x16x32_bf16(af[mi], bb[ni], acc[mi][ni], 0, 0, 0);
    }
  };

  const int nk = Hsz >> 6;   // 32
  STAGE(0, 0);
  for (int kt = 0; kt < nk - 1; ++kt) {
    STAGE(kt + 1, (kt + 1) & 1);
    asm volatile("s_waitcnt vmcnt(8)" ::: "memory");
    __builtin_amdgcn_s_barrier();
    __builtin_amdgcn_sched_barrier(0);
    COMPUTE(kt & 1);
    asm volatile("s_waitcnt lgkmcnt(0)" ::: "memory");
    __builtin_amdgcn_s_barrier();
  }
  asm volatile("s_waitcnt vmcnt(0)" ::: "memory");
  __builtin_amdgcn_s_barrier();
  __builtin_amdgcn_sched_barrier(0);
  COMPUTE((nk - 1) & 1);

#pragma unroll
  for (int mi = 0; mi < 4; ++mi) {
#pragma unroll
    for (int nh = 0; nh < 2; ++nh) {
      const int ni = nh << 1;
      const int j = (((bn0 + wc + (ni << 4)) >> 5) << 4) + fc;   // [0,512)
      const float bm = bias[j], blv = bias[512 + j];
#pragma unroll
      for (int r = 0; r < 4; ++r) {
        const int m = bm0 + wr + (mi << 4) + (fh << 2) + r;
        int b, t;
        if (PERSTEP) { b = m; t = t_arg; }
        else { b = m >> 6; t = m & 63; if (t == TM1) continue; }
        const float mv = acc[mi][ni][r] + bm;
        const float lv = acc[mi][ni + 1][r] + blv;
        const long noff = ((long)b * TM1 + t) * Ssz + j;
        const float sv = mv + (1.f + expf(lv)) * noise[noff];
        out[outS + (long)b * (Tsz * Ssz) + (long)(t + 1) * Ssz + j] = sv;
        out[outM + noff] = mv;
        out[outLV + noff] = lv;
        if (PERSTEP) sbOut[b * Ssz + j] = f2bf(sv);
      }
    }
  }
}

// ---------------------------------------------------------------------------
// small kernels
// ---------------------------------------------------------------------------
__global__ void conv_f2b(const float* __restrict__ src, short* __restrict__ dst, long n) {
  long i = ((long)blockIdx.x * 256 + threadIdx.x) * 4;
  const long stride = (long)gridDim.x * 1024;
  for (; i < n; i += stride) {
    float4 v = *(const float4*)(src + i);
    s16x4 o;
    o[0] = f2bf(v.x); o[1] = f2bf(v.y); o[2] = f2bf(v.z); o[3] = f2bf(v.w);
    *(s16x4*)(dst + i) = o;
  }
}

// dst[perm(n)][k] = src[(k0+k)*srcld + n]; PERM interleaves mean/logvar pairs
template<int PERM>
__global__ void transp(const float* __restrict__ src, short* __restrict__ dst,
                       int srcld, int k0, int K, int N) {
  __shared__ float t[32][33];
  const int tx = threadIdx.x, ty = threadIdx.y;
  const int kb = blockIdx.y << 5, nb = blockIdx.x << 5;
#pragma unroll
  for (int i = ty; i < 32; i += 8)
    t[i][tx] = src[(long)(k0 + kb + i) * srcld + nb + tx];
  __syncthreads();
#pragma unroll
  for (int i = ty; i < 32; i += 8) {
    int n = nb + i, drow = n;
    if (PERM) { const int j = n & 511, lv = n >> 9; drow = ((j >> 4) << 5) | (lv << 4) | (j & 15); }
    dst[(long)drow * K + kb + tx] = f2bf(t[tx][i]);
  }
}

__global__ void init_kernel(const float* __restrict__ ph, const float* __restrict__ ps,
                            float* __restrict__ out, short* __restrict__ hb, short* __restrict__ sb) {
  const int idx = blockIdx.x * 256 + threadIdx.x;
  const int b = idx >> 11, n = idx & 2047;
  const float h = ph[idx];
  out[(long)b * (Tsz * Hsz) + n] = h;
  hb[idx] = f2bf(h);
  if (n < Ssz) {
    const int sidx = b * Ssz + n;
    const float s = ps[sidx];
    out[OUT_PS + (long)b * (Tsz * Ssz) + n] = s;
    out[OUT_QS + (long)b * (Tsz * Ssz) + n] = s;
    sb[sidx] = f2bf(s);
  }
}

// GRU fusion; also logs h (bf16) into Hall row (b*64 + t) for the batched
// prior pass.  hallRow = Hall + t*Hsz, b-stride = 64*Hsz.
__global__ void gru_kernel(const float* __restrict__ gi, const float* __restrict__ gh,
                           const float* __restrict__ b_ih, const float* __restrict__ b_hh,
                           const float* __restrict__ hold, float* __restrict__ hnew,
                           short* __restrict__ hb, short* __restrict__ hallRow) {
  const int idx = blockIdx.x * 256 + threadIdx.x;
  const int b = idx >> 11, n = idx & 2047;
  const long gb = (long)b * (3 * Hsz) + n;
  const float ir = gi[gb] + b_ih[n],                 hr = gh[gb] + b_hh[n];
  const float iz = gi[gb + Hsz] + b_ih[Hsz + n],     hz = gh[gb + Hsz] + b_hh[Hsz + n];
  const float in_ = gi[gb + 2 * Hsz] + b_ih[2 * Hsz + n];
  const float hn = gh[gb + 2 * Hsz] + b_hh[2 * Hsz + n];
  const float r = 1.f / (1.f + expf(-(ir + hr)));
  const float z = 1.f / (1.f + expf(-(iz + hz)));
  const float nn = tanhf(in_ + r * hn);
  const float h = (1.f - z) * nn + z * hold[(long)b * (Tsz * Hsz) + n];
  hnew[(long)b * (Tsz * Hsz) + n] = h;
  const short hbf = f2bf(h);
  hb[idx] = hbf;
  hallRow[(long)b * (Tsz * Hsz) + n] = hbf;
}

// ho reducer: o = bf16(relu(sum_{kc<4} p[kc] + ci[b*64+t]))
__global__ void reduce_relu(const float* __restrict__ p, const short* __restrict__ ci,
                            short* __restrict__ o, int t) {
  const int i = (blockIdx.x * 256 + threadIdx.x) * 4;
  const int b = i >> 11, n = i & 2047;
  f32x4 v = *(const f32x4*)&p[i];
  v += *(const f32x4*)&p[PSH + i];
  v += *(const f32x4*)&p[2 * PSH + i];
  v += *(const f32x4*)&p[3 * PSH + i];
  const s16x4 c = *(const s16x4*)&ci[((long)b * Tsz + t) * Hsz + n];
  s16x4 ov;
#pragma unroll
  for (int k = 0; k < 4; ++k) ov[k] = f2bf(fmaxf(v[k] + bf2f(c[k]), 0.f));
  *(s16x4*)&o[i] = ov;
}

static GArg mk(const short* A, int lda, const short* Bt, int ldb, const float* bias,
               const short* Ci, long ldci, float* oF, int ldoF, long pstride,
               short* oB, int ldoB) {
  GArg g; g.A = A; g.Bt = Bt; g.bias = bias; g.Ci = Ci; g.ldci = ldci;
  g.oF = oF; g.oB = oB; g.lda = lda; g.ldb = ldb; g.ldoF = ldoF; g.ldoB = ldoB;
  g.pstride = pstride;
  return g;
}

extern "C" void kernel_launch(void* const* d_in, const int* in_sizes, int n_in,
                              void* d_out, int out_size, void* d_ws, size_t ws_size,
                              hipStream_t stream) {
  const float* prev_hidden = (const float*)d_in[0];
  const float* prev_state  = (const float*)d_in[1];
  const float* actions     = (const float*)d_in[2];
  const float* obs         = (const float*)d_in[3];
  const float* prior_noise = (const float*)d_in[4];
  const float* post_noise  = (const float*)d_in[5];
  const float* W_sa = (const float*)d_in[6];
  const float* b_sa = (const float*)d_in[7];
  const float* W_ih = (const float*)d_in[8];
  const float* W_hh = (const float*)d_in[9];
  const float* b_ih = (const float*)d_in[10];
  const float* b_hh = (const float*)d_in[11];
  const float* W_ha = (const float*)d_in[12];
  const float* b_ha = (const float*)d_in[13];
  const float* W_prior = (const float*)d_in[14];
  const float* b_prior = (const float*)d_in[15];
  const float* W_ho = (const float*)d_in[16];
  const float* b_ho = (const float*)d_in[17];
  const float* W_post = (const float*)d_in[18];
  const float* b_post = (const float*)d_in[19];
  float* out = (float*)d_out;

  char* p = (char*)d_ws;
  auto alloc = [&](size_t bytes) { char* r = p; p += (bytes + 255) & ~(size_t)255; return r; };
  short* Wih_b   = (short*)alloc(3L * Hsz * Hsz * 2);
  short* Whh_b   = (short*)alloc(3L * Hsz * Hsz * 2);
  short* Wt_sa_s = (short*)alloc((long)Hsz * Ssz * 2);
  short* Wt_sa_a = (short*)alloc((long)Hsz * Asz * 2);
  short* Wt_ha_h = (short*)alloc((long)Hsz * Hsz * 2);
  short* Wt_ha_a = (short*)alloc((long)Hsz * Asz * 2);
  short* Wt_ho_h = (short*)alloc((long)Hsz * Hsz * 2);
  short* Wt_ho_o = (short*)alloc((long)Hsz * Esz * 2);
  short* Wt_pr   = (short*)alloc(2L * Ssz * Hsz * 2);      // PERMUTED cols
  short* Wt_po   = (short*)alloc(2L * Ssz * Hsz * 2);      // PERMUTED cols
  short* obs_b   = (short*)alloc((long)Bsz * Tsz * Esz * 2);   // aliased in scan
  short* act_b   = (short*)alloc((long)Bsz * Tsz * Asz * 2);
  short* a_pre   = (short*)alloc((long)Bsz * Tsz * Hsz * 2);   // -> ha_all after scan
  short* ha_a    = (short*)alloc((long)Bsz * Tsz * Hsz * 2);
  short* ho_o    = (short*)alloc((long)Bsz * Tsz * Hsz * 2);
  short* Hall_b  = (short*)alloc((long)Bsz * Tsz * Hsz * 2);   // h_{t+1} at row b*64+t
  short* s_b     = (short*)alloc((long)Bsz * Ssz * 2);
  short* h_b     = (short*)alloc((long)Bsz * Hsz * 2);
  short* sa_b    = (short*)alloc((long)Bsz * Hsz * 2);
  short* ho_b    = (short*)alloc((long)Bsz * Hsz * 2);
  char* q = (char*)obs_b;                     // alias region (dead after precompute)
  auto alias = [&](size_t bytes) { char* r = q; q += (bytes + 255) & ~(size_t)255; return r; };
  float* gi_f    = (float*)alias((long)Bsz * 3 * Hsz * 4);
  float* gh_f    = (float*)alias((long)Bsz * 3 * Hsz * 4);
  float* ho_p    = (float*)alias(4L * PSH * 4);
  (void)ws_size; (void)in_sizes; (void)n_in; (void)out_size;

  conv_f2b<<<4096, 256, 0, stream>>>(obs,  obs_b, (long)Bsz * Tsz * Esz);
  conv_f2b<<<1024, 256, 0, stream>>>(actions, act_b, (long)Bsz * Tsz * Asz);
  conv_f2b<<<4096, 256, 0, stream>>>(W_ih, Wih_b, 3L * Hsz * Hsz);
  conv_f2b<<<4096, 256, 0, stream>>>(W_hh, Whh_b, 3L * Hsz * Hsz);

  dim3 tb(32, 8);
  transp<0><<<dim3(Hsz / 32, Ssz / 32), tb, 0, stream>>>(W_sa, Wt_sa_s, Hsz, 0,   Ssz, Hsz);
  transp<0><<<dim3(Hsz / 32, Asz / 32), tb, 0, stream>>>(W_sa, Wt_sa_a, Hsz, Ssz, Asz, Hsz);
  transp<0><<<dim3(Hsz / 32, Hsz / 32), tb, 0, stream>>>(W_ha, Wt_ha_h, Hsz, 0,   Hsz, Hsz);
  transp<0><<<dim3(Hsz / 32, Asz / 32), tb, 0, stream>>>(W_ha, Wt_ha_a, Hsz, Hsz, Asz, Hsz);
  transp<0><<<dim3(Hsz / 32, Hsz / 32), tb, 0, stream>>>(W_ho, Wt_ho_h, Hsz, 0,   Hsz, Hsz);
  transp<0><<<dim3(Hsz / 32, Esz / 32), tb, 0, stream>>>(W_ho, Wt_ho_o, Hsz, Hsz, Esz, Hsz);
  transp<1><<<dim3(2 * Ssz / 32, Hsz / 32), tb, 0, stream>>>(W_prior, Wt_pr, 2 * Ssz, 0, Hsz, 2 * Ssz);
  transp<1><<<dim3(2 * Ssz / 32, Hsz / 32), tb, 0, stream>>>(W_post,  Wt_po, 2 * Ssz, 0, Hsz, 2 * Ssz);

  init_kernel<<<2048, 256, 0, stream>>>(prev_hidden, prev_state, out, h_b, s_b);

  // t-independent precomputes (before scan: scan aliases obs_b region)
  {
    GArg g0 = mk(act_b, Asz, Wt_sa_a, Asz, b_sa, nullptr, 0, nullptr, 0, 0, a_pre, Hsz);
    GArg g1 = mk(act_b, Asz, Wt_ha_a, Asz, b_ha, nullptr, 0, nullptr, 0, 0, ha_a, Hsz);
    gemm_bt<1, 0, 0, 0, 1><<<dim3(Hsz / 128, (Bsz * Tsz) / 128, 2), 256, 0, stream>>>(g0, g1, 1, Asz);
  }
  {
    GArg g0 = mk(obs_b, Esz, Wt_ho_o, Esz, b_ho, nullptr, 0, nullptr, 0, 0, ho_o, Hsz);
    gemm_bt<1, 0, 0, 0, 1><<<dim3(Hsz / 128, (Bsz * Tsz) / 128, 1), 256, 0, stream>>>(g0, g0, 0, Esz);
  }

  // ---- sequential scan (critical path only: posterior chain) ---------------
  const long ldPre = (long)Tsz * Hsz;
  for (int t = 0; t < TM1; ++t) {
    // sa = relu(s @ Wsa_s + a_pre[t])                     [256,2048] K=512
    {
      GArg g0 = mk(s_b, Ssz, Wt_sa_s, Ssz, nullptr, a_pre + (long)t * Hsz, ldPre,
                   nullptr, 0, 0, sa_b, Hsz);
      gemm_bt<0, 1, 1, 0, 1><<<dim3(16, 2, 1), 256, 0, stream>>>(g0, g0, 0, Ssz);
    }
    // gi = sa @ Wih^T ; gh = h @ Whh^T                    [256,6144] K=2048
    {
      GArg g0 = mk(sa_b, Hsz, Wih_b, Hsz, nullptr, nullptr, 0, gi_f, 3 * Hsz, 0, nullptr, 0);
      GArg g1 = mk(h_b,  Hsz, Whh_b, Hsz, nullptr, nullptr, 0, gh_f, 3 * Hsz, 0, nullptr, 0);
      gemm_bt<0, 0, 0, 1, 0><<<dim3(48, 2, 2), 256, 0, stream>>>(g0, g1, 1, Hsz);
    }
    gru_kernel<<<2048, 256, 0, stream>>>(gi_f, gh_f, b_ih, b_hh,
                                         out + (long)t * Hsz, out + (long)(t + 1) * Hsz,
                                         h_b, Hall_b + (long)t * Hsz);
    // ho partials, split-K=4                              [256,2048] K=2048
    {
      GArg g0 = mk(h_b, Hsz, Wt_ho_h, Hsz, nullptr, nullptr, 0, ho_p, Hsz, PSH, nullptr, 0);
      gemm_bt<0, 0, 0, 1, 0><<<dim3(16, 2, 4), 256, 0, stream>>>(g0, g0, 0, Hsz / 4);
    }
    reduce_relu<<<512, 256, 0, stream>>>(ho_p, ho_o, ho_b, t);
    // post GEMM + fused posterior rsample                 [256,1024] K=2048
    gemm_sample<1><<<dim3(8, 2, 1), 256, 0, stream>>>(
        ho_b, Wt_po, b_post, post_noise, out, s_b, OUT_QS, OUT_QM, OUT_QLV, t);
  }

  // ---- batched prior branch (off critical path) ----------------------------
  // ha_all = relu(Hall @ Wha_h + ha_a)   [16384,2048] K=2048  -> a_pre buffer
  {
    GArg g0 = mk(Hall_b, Hsz, Wt_ha_h, Hsz, nullptr, ha_a, Hsz, nullptr, 0, 0, a_pre, Hsz);
    gemm_bt<0, 1, 1, 0, 1><<<dim3(16, 128, 1), 256, 0, stream>>>(g0, g0, 0, Hsz);
  }
  // prior GEMM + fused prior rsample     [16384,1024] K=2048
  gemm_sample<0><<<dim3(8, 128, 1), 256, 0, stream>>>(
      a_pre, Wt_pr, b_prior, prior_noise, out, nullptr, OUT_PS, OUT_PM, OUT_PLV, 0);
}